// Round 6
// baseline (490.470 us; speedup 1.0000x reference)
//
#include <hip/hip_runtime.h>
#include <hip/hip_bf16.h>

// ---------------- problem constants ----------------
#define OUT_C 256
#define IN_C  256
#define KC    26
#define KD    25
#define BATCH 32
#define LEN   1024
#define LOUT  (LEN - KD + 1)   // 1000

// ---------------- conv tiling ----------------
#define BM 128                 // o per block
#define BL 128                 // l per block
#define ICH 64                 // i per staged chunk
#define NIC (IN_C / ICH)       // 4
#define XROWS (BL + KD - 1)    // 152 l-rows staged (row = 64 bf16 = 128B)
#define SLABSZ (OUT_C * ICH)   // elems per (d,ic) K slab = 16384

typedef short bf16x8 __attribute__((ext_vector_type(8)));
typedef float f32x4  __attribute__((ext_vector_type(4)));

static __device__ __forceinline__ unsigned short f2bf(float f) {
    unsigned int u = __float_as_uint(f);
    u = (u + 0x7FFFu + ((u >> 16) & 1u)) >> 16;   // RNE
    return (unsigned short)u;
}
static __device__ __forceinline__ float bf2f(unsigned short h) {
    return __uint_as_float(((unsigned int)h) << 16);
}

// ---------------------------------------------------------------------------
// Kernel 1: build effective conv kernel, split into bf16 hi/lo.
// Layout [d][ic][o][64 i] (plain, NO swizzle): the conv kernel streams A
// fragments straight global->VGPR, so fragment addressing is native here.
// ---------------------------------------------------------------------------
__global__ __launch_bounds__(256) void build_kernel(
    const float* __restrict__ weight,
    const float* __restrict__ sign,
    const float* __restrict__ P,
    const float* __restrict__ SIG,
    unsigned short* __restrict__ Kh,
    unsigned short* __restrict__ Kl)
{
    int tid = blockIdx.x * blockDim.x + threadIdx.x;   // o*IN_C + i
    if (tid >= OUT_C * IN_C) return;
    const int o = tid / IN_C;
    const int i = tid % IN_C;
    const int base = tid * KC;

    float K[KD];
#pragma unroll
    for (int d = 0; d < KD; ++d) K[d] = 0.f;

    for (int c = 0; c < KC; ++c) {
        const float w   = weight[base + c] * sign[base + c];
        const float pc  = P[base + c] + (float)(KD / 2);
        const float s   = fabsf(SIG[base + c]) + 0.27f;
        const float inv = 1.f / s;
        float e[KD];
        float sum = 0.f;
#pragma unroll
        for (int d = 0; d < KD; ++d) {
            const float t = ((float)d - pc) * inv;
            e[d] = __expf(-0.5f * t * t);
            sum += e[d];
        }
        const float wn = w / (sum + 1e-7f);
#pragma unroll
        for (int d = 0; d < KD; ++d) K[d] += wn * e[d];
    }

    const int ic = i >> 6;         // 64-i chunk
    const int il = i & 63;         // i within chunk
#pragma unroll
    for (int d = 0; d < KD; ++d) {
        const int off = (d * NIC + ic) * SLABSZ + o * ICH + il;
        const float v = K[d];
        const unsigned short h = f2bf(v);
        const unsigned short l = f2bf(v - bf2f(h));
        Kh[off] = h;
        Kl[off] = l;
    }
}

// ---------------------------------------------------------------------------
// Kernel 2: conv1d as implicit GEMM on mfma_f32_16x16x32_bf16, 3-product
// hi/lo split (near-fp32 accuracy).
//   D[m=o][n=l]; A = K (streamed GLOBAL->VGPR, no LDS), B = x (LDS).
//   k-tile = 16 consecutive i at fixed d; A and B share the same k-map,
//   so the contraction is exact under any HW k-permutation.
// Block: 256 thr = 4 waves (2x2), tile 128o x 128l, wave tile 64x64.
// Inner structure per ic-chunk: [stage x -> LDS; barrier; 25d x 2kt
//   BARRIER-FREE phases (prefetch next A-frags into alternate reg buffer,
//   48 MFMA from current buffer); barrier]. 2 barriers per chunk total.
// LDS 38.9KB: xs only (transposed [152 l][64 i] hi/lo, XOR-swizzled slots).
// ---------------------------------------------------------------------------
__global__ __launch_bounds__(256, 2) void conv_kernel(
    const float* __restrict__ x,
    const unsigned short* __restrict__ Kh,
    const unsigned short* __restrict__ Kl,
    float* __restrict__ out)
{
    __shared__ __align__(16) unsigned short xs_h[XROWS * ICH];  // 19456 B
    __shared__ __align__(16) unsigned short xs_l[XROWS * ICH];

    const int tid = threadIdx.x;
    const unsigned int Bid = blockIdx.x;
    const int ot = Bid & 1;                 // o-half: fixed per XCD parity (L2 reuse)
    const int lt = (Bid >> 1) & 7;          // l tile
    const int b  = Bid >> 4;                // batch
    const int o0 = ot * BM;
    const int l0 = lt * BL;

    const int lane = tid & 63;
    const int wid  = tid >> 6;              // 0..3
    const int wm   = wid >> 1;              // wave o-half (64)
    const int wn   = wid & 1;               // wave l-half (64)
    const int n16  = lane & 15;
    const int g    = lane >> 4;             // 0..3 (k-group)

    // lane-fixed element offset of this lane's A-fragment within a K slab
    const int kbase = (o0 + wm * 64 + n16) * ICH + g * 8;

    f32x4 acc[4][4] = {};
    bf16x8 Ah0[4], Al0[4], Ah1[4], Al1[4];   // 2-deep kt-phase double buffer

#define LOADA(BUFH, BUFL, SLAB, KT)                                       \
    {                                                                     \
        const int _e0 = (SLAB) * SLABSZ + kbase + (KT) * 32;              \
        _Pragma("unroll")                                                 \
        for (int mt = 0; mt < 4; ++mt) {                                  \
            BUFH[mt] = *(const bf16x8*)&Kh[_e0 + mt * (16 * ICH)];        \
            BUFL[mt] = *(const bf16x8*)&Kl[_e0 + mt * (16 * ICH)];        \
        }                                                                 \
    }

#define COMPUTE(AH, AL, KT, D)                                            \
    {                                                                     \
        bf16x8 bh[4], bl[4];                                              \
        _Pragma("unroll")                                                 \
        for (int nt = 0; nt < 4; ++nt) {                                  \
            const int row  = wn * 64 + nt * 16 + n16 + (D);               \
            const int slot = ((KT) * 4 + g) ^ (row & 7);                  \
            const int pos  = row * ICH + slot * 8;                        \
            bh[nt] = *(const bf16x8*)&xs_h[pos];                          \
            bl[nt] = *(const bf16x8*)&xs_l[pos];                          \
        }                                                                 \
        _Pragma("unroll")                                                 \
        for (int mt = 0; mt < 4; ++mt)                                    \
            _Pragma("unroll")                                             \
            for (int nt = 0; nt < 4; ++nt) {                              \
                acc[mt][nt] = __builtin_amdgcn_mfma_f32_16x16x32_bf16(    \
                    AL[mt], bh[nt], acc[mt][nt], 0, 0, 0);                \
                acc[mt][nt] = __builtin_amdgcn_mfma_f32_16x16x32_bf16(    \
                    AH[mt], bl[nt], acc[mt][nt], 0, 0, 0);                \
                acc[mt][nt] = __builtin_amdgcn_mfma_f32_16x16x32_bf16(    \
                    AH[mt], bh[nt], acc[mt][nt], 0, 0, 0);                \
            }                                                             \
    }

    // prologue: issue phase-0 (ic=0, d=0, kt=0) A-fragment loads
    int slab = 0;                            // slab index = d*NIC + ic
    LOADA(Ah0, Al0, 0, 0);

#pragma unroll 1
    for (int ic = 0; ic < NIC; ++ic) {
        // ---- stage x chunk: transpose + hi/lo split + XOR swizzle.
        // 8 i-values packed per uint4 (swizzle slot constant across the
        // 8-i octave -> one aligned b128 write per pair of arrays).
        const int xbase = (b * IN_C + ic * ICH) * LEN;
        for (int idx = tid; idx < (ICH / 8) * XROWS; idx += 256) {   // 1216
            const int c8 = idx / XROWS;          // i octave 0..7
            const int r  = idx - c8 * XROWS;     // l row 0..151
            const int gl = l0 + r;
            const int ci = c8 * 8;
            float v[8];
#pragma unroll
            for (int j = 0; j < 8; ++j)
                v[j] = (gl < LEN) ? x[xbase + (ci + j) * LEN + gl] : 0.f;
            unsigned int ph[4], pl[4];
#pragma unroll
            for (int j = 0; j < 4; ++j) {
                const unsigned short h0  = f2bf(v[2 * j]);
                const unsigned short h1  = f2bf(v[2 * j + 1]);
                const unsigned short l0s = f2bf(v[2 * j] - bf2f(h0));
                const unsigned short l1s = f2bf(v[2 * j + 1] - bf2f(h1));
                ph[j] = (unsigned int)h0 | ((unsigned int)h1 << 16);
                pl[j] = (unsigned int)l0s | ((unsigned int)l1s << 16);
            }
            const int slot = r * 8 + (c8 ^ (r & 7));    // uint4 index
            ((uint4*)xs_h)[slot] = make_uint4(ph[0], ph[1], ph[2], ph[3]);
            ((uint4*)xs_l)[slot] = make_uint4(pl[0], pl[1], pl[2], pl[3]);
        }
        __syncthreads();   // xs visible; no LDS writes until after d-loop

#pragma unroll 1
        for (int d = 0; d < KD; ++d) {
            const int slabNext = (d < KD - 1) ? slab + NIC
                               : (ic < NIC - 1 ? ic + 1 : slab);
            // phase kt=0: prefetch (slab, kt=1), compute buffer 0
            LOADA(Ah1, Al1, slab, 1);
            COMPUTE(Ah0, Al0, 0, d);
            // phase kt=1: prefetch (slabNext, kt=0), compute buffer 1
            LOADA(Ah0, Al0, slabNext, 0);
            COMPUTE(Ah1, Al1, 1, d);
            slab = slabNext;
        }
        __syncthreads();   // all xs reads done before next chunk overwrites
    }

#undef LOADA
#undef COMPUTE

    // ---- epilogue: C/D layout col=lane&15 (=l), row=(lane>>4)*4+reg (=o)
#pragma unroll
    for (int mt = 0; mt < 4; ++mt)
#pragma unroll
        for (int nt = 0; nt < 4; ++nt) {
            const int l = l0 + wn * 64 + nt * 16 + n16;
            if (l < LOUT) {
#pragma unroll
                for (int r = 0; r < 4; ++r) {
                    const int o = o0 + wm * 64 + mt * 16 + g * 4 + r;
                    out[(b * OUT_C + o) * LOUT + l] = acc[mt][nt][r];
                }
            }
        }
}

// ---------------------------------------------------------------------------
extern "C" void kernel_launch(void* const* d_in, const int* in_sizes, int n_in,
                              void* d_out, int out_size, void* d_ws, size_t ws_size,
                              hipStream_t stream)
{
    (void)in_sizes; (void)n_in; (void)out_size; (void)ws_size;

    const float* x      = (const float*)d_in[0];
    const float* weight = (const float*)d_in[1];
    const float* sign   = (const float*)d_in[2];
    const float* P      = (const float*)d_in[3];
    const float* SIG    = (const float*)d_in[4];
    float*       out    = (float*)d_out;

    // workspace: Kh then Kl, each 25*4*256*64 = 1,638,400 bf16 (3.28 MB)
    unsigned short* Kh = (unsigned short*)d_ws;
    unsigned short* Kl = Kh + (size_t)KD * NIC * SLABSZ;

    build_kernel<<<dim3((OUT_C * IN_C + 255) / 256), dim3(256), 0, stream>>>(
        weight, sign, P, SIG, Kh, Kl);

    // 512 blocks: Bid&1 = o-half (constant per XCD under %8 round-robin),
    // bits1-3 = l tile, bits4+ = batch
    conv_kernel<<<dim3(512), dim3(256), 0, stream>>>(x, Kh, Kl, out);
}

// Round 7
// 483.674 us; speedup vs baseline: 1.0141x; 1.0141x over previous
//
#include <hip/hip_runtime.h>
#include <hip/hip_bf16.h>

// ---------------- problem constants ----------------
#define OUT_C 256
#define IN_C  256
#define KC    26
#define KD    25
#define BATCH 32
#define LEN   1024
#define LOUT  (LEN - KD + 1)   // 1000

// ---------------- conv tiling ----------------
#define BM 128                 // o per block
#define BL 128                 // l per block
#define ICH 64                 // i per staged chunk
#define NIC (IN_C / ICH)       // 4
#define XROWS (BL + KD - 1)    // 152 l-rows staged (row = 64 bf16 = 128B)
#define SLABSZ (OUT_C * ICH)   // elems per (d,ic) K slab = 16384
#define CCHUNK 13              // build kernel c-chunk (26 = 2*13)

typedef short bf16x8 __attribute__((ext_vector_type(8)));
typedef float f32x4  __attribute__((ext_vector_type(4)));

static __device__ __forceinline__ unsigned short f2bf(float f) {
    unsigned int u = __float_as_uint(f);
    u = (u + 0x7FFFu + ((u >> 16) & 1u)) >> 16;   // RNE
    return (unsigned short)u;
}
static __device__ __forceinline__ float bf2f(unsigned short h) {
    return __uint_as_float(((unsigned int)h) << 16);
}

// ---------------------------------------------------------------------------
// Kernel 1: build effective conv kernel, split into bf16 hi/lo.
// Layout [d][ic][o][64 i] (plain): conv streams A straight global->VGPR.
// v2: block = one o (256 threads = 256 i's). Inputs staged to LDS with
// COALESCED loads in two c-chunks (round-6 version did 104 uncoalesced
// 104B-strided loads per thread at 1 wave/SIMD -> 79 us of pure latency).
// Math is op-identical to round 6 -> bit-identical K.
// ---------------------------------------------------------------------------
__global__ __launch_bounds__(256) void build_kernel(
    const float* __restrict__ weight,
    const float* __restrict__ sign,
    const float* __restrict__ P,
    const float* __restrict__ SIG,
    unsigned short* __restrict__ Kh,
    unsigned short* __restrict__ Kl)
{
    __shared__ float Ws[256 * CCHUNK];   // w*sign
    __shared__ float Ps[256 * CCHUNK];   // P + 12
    __shared__ float Ss[256 * CCHUNK];   // |SIG| + 0.27

    const int tid = threadIdx.x;         // i
    const int o   = blockIdx.x;
    const int gbase = o * IN_C * KC;     // block's contiguous span (floats)

    float K[KD];
#pragma unroll
    for (int d = 0; d < KD; ++d) K[d] = 0.f;

#pragma unroll 1
    for (int cc = 0; cc < KC; cc += CCHUNK) {
        __syncthreads();   // previous chunk's LDS reads done
        // ---- stage: 256 rows x 13 c's of each array, coalesced-ish
        for (int q = tid; q < 256 * CCHUNK; q += 256) {
            const int p = q / CCHUNK;
            const int c = q - p * CCHUNK;
            const int gidx = gbase + p * KC + cc + c;
            Ws[q] = weight[gidx] * sign[gidx];
            Ps[q] = P[gidx] + (float)(KD / 2);
            Ss[q] = fabsf(SIG[gidx]) + 0.27f;
        }
        __syncthreads();

        // ---- compute (from LDS; stride 13 is odd -> conflict-free)
#pragma unroll 1
        for (int c = 0; c < CCHUNK; ++c) {
            const float w   = Ws[tid * CCHUNK + c];
            const float pc  = Ps[tid * CCHUNK + c];
            const float s   = Ss[tid * CCHUNK + c];
            const float inv = 1.f / s;
            float e[KD];
            float sum = 0.f;
#pragma unroll
            for (int d = 0; d < KD; ++d) {
                const float t = ((float)d - pc) * inv;
                e[d] = __expf(-0.5f * t * t);
                sum += e[d];
            }
            const float wn = w / (sum + 1e-7f);
#pragma unroll
            for (int d = 0; d < KD; ++d) K[d] += wn * e[d];
        }
    }

    const int ic = tid >> 6;       // 64-i chunk
    const int il = tid & 63;       // i within chunk
#pragma unroll
    for (int d = 0; d < KD; ++d) {
        const int off = (d * NIC + ic) * SLABSZ + o * ICH + il;
        const float v = K[d];
        const unsigned short h = f2bf(v);
        const unsigned short l = f2bf(v - bf2f(h));
        Kh[off] = h;
        Kl[off] = l;
    }
}

// ---------------------------------------------------------------------------
// Kernel 2: conv1d as implicit GEMM on mfma_f32_16x16x32_bf16, 3-product
// hi/lo split. A = K streamed global->VGPR, B = x via LDS.
// v2 schedule fix: next-phase A-loads are DISTRIBUTED per-mt inside the
// MFMA sections (round-6 issued half the loads ~8 instrs before use ->
// full L2/L3 latency exposed every 2nd phase -> MfmaUtil 33%). Now every
// load is issued in section mt of phase p and consumed in section mt of
// phase p+1: uniform ~3-section (~700 cyc) cover.
// ---------------------------------------------------------------------------
__global__ __launch_bounds__(256, 2) void conv_kernel(
    const float* __restrict__ x,
    const unsigned short* __restrict__ Kh,
    const unsigned short* __restrict__ Kl,
    float* __restrict__ out)
{
    __shared__ __align__(16) unsigned short xs_h[XROWS * ICH];  // 19456 B
    __shared__ __align__(16) unsigned short xs_l[XROWS * ICH];

    const int tid = threadIdx.x;
    const unsigned int Bid = blockIdx.x;
    const int ot = Bid & 1;                 // o-half: fixed per XCD parity
    const int lt = (Bid >> 1) & 7;          // l tile
    const int b  = Bid >> 4;                // batch
    const int o0 = ot * BM;
    const int l0 = lt * BL;

    const int lane = tid & 63;
    const int wid  = tid >> 6;              // 0..3
    const int wm   = wid >> 1;              // wave o-half (64)
    const int wn   = wid & 1;               // wave l-half (64)
    const int n16  = lane & 15;
    const int g    = lane >> 4;             // 0..3 (k-group)

    // lane-fixed element offset of this lane's A-fragment within a K slab
    const int kbase = (o0 + wm * 64 + n16) * ICH + g * 8;

    f32x4 acc[4][4] = {};
    bf16x8 A0h[4], A0l[4], A1h[4], A1l[4];  // kt-phase double buffer

#define LOAD_MT(BH, BL_, SLAB, KT, MT)                                    \
    {                                                                     \
        const int _e = (SLAB) * SLABSZ + kbase + (KT) * 32 + (MT) * (16 * ICH); \
        BH[MT]  = *(const bf16x8*)&Kh[_e];                                \
        BL_[MT] = *(const bf16x8*)&Kl[_e];                                \
    }

// one kt-phase: read B frags, then 4 mt-sections of
// [issue next-phase A-load for mt; 12 MFMAs on current A[mt]]
#define PHASE(CH, CL, NH, NL, KT, NSLAB, NKT, D)                          \
    {                                                                     \
        bf16x8 bh[4], bl[4];                                              \
        _Pragma("unroll")                                                 \
        for (int nt = 0; nt < 4; ++nt) {                                  \
            const int row  = wn * 64 + nt * 16 + n16 + (D);               \
            const int slot = ((KT) * 4 + g) ^ (row & 7);                  \
            const int pos  = row * ICH + slot * 8;                        \
            bh[nt] = *(const bf16x8*)&xs_h[pos];                          \
            bl[nt] = *(const bf16x8*)&xs_l[pos];                          \
        }                                                                 \
        _Pragma("unroll")                                                 \
        for (int mt = 0; mt < 4; ++mt) {                                  \
            LOAD_MT(NH, NL, NSLAB, NKT, mt);                              \
            _Pragma("unroll")                                             \
            for (int nt = 0; nt < 4; ++nt) {                              \
                acc[mt][nt] = __builtin_amdgcn_mfma_f32_16x16x32_bf16(    \
                    CL[mt], bh[nt], acc[mt][nt], 0, 0, 0);                \
                acc[mt][nt] = __builtin_amdgcn_mfma_f32_16x16x32_bf16(    \
                    CH[mt], bl[nt], acc[mt][nt], 0, 0, 0);                \
                acc[mt][nt] = __builtin_amdgcn_mfma_f32_16x16x32_bf16(    \
                    CH[mt], bh[nt], acc[mt][nt], 0, 0, 0);                \
            }                                                             \
        }                                                                 \
    }

    // prologue: load phase-0 (ic=0, d=0, kt=0) A-fragments
    int slab = 0;                            // slab index = d*NIC + ic
#pragma unroll
    for (int mt = 0; mt < 4; ++mt) LOAD_MT(A0h, A0l, 0, 0, mt);

#pragma unroll 1
    for (int ic = 0; ic < NIC; ++ic) {
        // ---- stage x chunk: transpose + hi/lo split + XOR swizzle
        const int xbase = (b * IN_C + ic * ICH) * LEN;
        for (int idx = tid; idx < (ICH / 8) * XROWS; idx += 256) {   // 1216
            const int c8 = idx / XROWS;          // i octave 0..7
            const int r  = idx - c8 * XROWS;     // l row 0..151
            const int gl = l0 + r;
            const int ci = c8 * 8;
            float v[8];
#pragma unroll
            for (int j = 0; j < 8; ++j)
                v[j] = (gl < LEN) ? x[xbase + (ci + j) * LEN + gl] : 0.f;
            unsigned int ph[4], pl[4];
#pragma unroll
            for (int j = 0; j < 4; ++j) {
                const unsigned short h0  = f2bf(v[2 * j]);
                const unsigned short h1  = f2bf(v[2 * j + 1]);
                const unsigned short l0s = f2bf(v[2 * j] - bf2f(h0));
                const unsigned short l1s = f2bf(v[2 * j + 1] - bf2f(h1));
                ph[j] = (unsigned int)h0 | ((unsigned int)h1 << 16);
                pl[j] = (unsigned int)l0s | ((unsigned int)l1s << 16);
            }
            const int slot = r * 8 + (c8 ^ (r & 7));    // uint4 index
            ((uint4*)xs_h)[slot] = make_uint4(ph[0], ph[1], ph[2], ph[3]);
            ((uint4*)xs_l)[slot] = make_uint4(pl[0], pl[1], pl[2], pl[3]);
        }
        __syncthreads();   // xs visible; no LDS writes until after d-loop

#pragma unroll 1
        for (int d = 0; d < KD; ++d) {
            const int slabNext = (d < KD - 1) ? slab + NIC
                               : (ic < NIC - 1 ? ic + 1 : slab);
            // compute kt=0 from A0 (loaded during previous phase),
            // issue kt=1 loads of this slab into A1 (interleaved per-mt)
            PHASE(A0h, A0l, A1h, A1l, 0, slab, 1, d);
            // compute kt=1 from A1, issue next slab's kt=0 into A0
            PHASE(A1h, A1l, A0h, A0l, 1, slabNext, 0, d);
            slab = slabNext;
        }
        __syncthreads();   // all xs reads done before next chunk overwrites
    }

#undef LOAD_MT
#undef PHASE

    // ---- epilogue: C/D layout col=lane&15 (=l), row=(lane>>4)*4+reg (=o)
#pragma unroll
    for (int mt = 0; mt < 4; ++mt)
#pragma unroll
        for (int nt = 0; nt < 4; ++nt) {
            const int l = l0 + wn * 64 + nt * 16 + n16;
            if (l < LOUT) {
#pragma unroll
                for (int r = 0; r < 4; ++r) {
                    const int o = o0 + wm * 64 + mt * 16 + g * 4 + r;
                    out[(b * OUT_C + o) * LOUT + l] = acc[mt][nt][r];
                }
            }
        }
}

// ---------------------------------------------------------------------------
extern "C" void kernel_launch(void* const* d_in, const int* in_sizes, int n_in,
                              void* d_out, int out_size, void* d_ws, size_t ws_size,
                              hipStream_t stream)
{
    (void)in_sizes; (void)n_in; (void)out_size; (void)ws_size;

    const float* x      = (const float*)d_in[0];
    const float* weight = (const float*)d_in[1];
    const float* sign   = (const float*)d_in[2];
    const float* P      = (const float*)d_in[3];
    const float* SIG    = (const float*)d_in[4];
    float*       out    = (float*)d_out;

    // workspace: Kh then Kl, each 25*4*256*64 = 1,638,400 bf16 (3.28 MB)
    unsigned short* Kh = (unsigned short*)d_ws;
    unsigned short* Kl = Kh + (size_t)KD * NIC * SLABSZ;

    // one block per o; inputs LDS-staged coalesced
    build_kernel<<<dim3(OUT_C), dim3(256), 0, stream>>>(
        weight, sign, P, SIG, Kh, Kl);

    // 512 blocks: Bid&1 = o-half (constant per XCD under %8 round-robin),
    // bits1-3 = l tile, bits4+ = batch
    conv_kernel<<<dim3(512), dim3(256), 0, stream>>>(x, Kh, Kl, out);
}

// Round 10
// 473.860 us; speedup vs baseline: 1.0351x; 1.0207x over previous
//
#include <hip/hip_runtime.h>
#include <hip/hip_bf16.h>

// ---------------- problem constants ----------------
#define OUT_C 256
#define IN_C  256
#define KC    26
#define KD    25
#define BATCH 32
#define LEN   1024
#define LOUT  (LEN - KD + 1)   // 1000

// ---------------- conv tiling ----------------
#define BM 128                 // o per block
#define BL 128                 // l per block
#define ICH 64                 // i per staged chunk
#define NIC (IN_C / ICH)       // 4
#define XROWS (BL + KD - 1)    // 152 l-rows staged (row = 64 bf16 = 128B)
#define SLABSZ (OUT_C * ICH)   // elems per (d,ic) K slab = 16384
#define CCHUNK 13              // build kernel c-chunk (26 = 2*13)

typedef short bf16x8 __attribute__((ext_vector_type(8)));
typedef float f32x4  __attribute__((ext_vector_type(4)));

static __device__ __forceinline__ unsigned short f2bf(float f) {
    unsigned int u = __float_as_uint(f);
    u = (u + 0x7FFFu + ((u >> 16) & 1u)) >> 16;   // RNE
    return (unsigned short)u;
}
static __device__ __forceinline__ float bf2f(unsigned short h) {
    return __uint_as_float(((unsigned int)h) << 16);
}

// ---------------------------------------------------------------------------
// Kernel 1: build effective conv kernel, split into bf16 hi/lo.
// Layout [d][ic][o][64 i] (plain): conv streams A straight global->VGPR.
// UNCHANGED since round 7 (bit-identical K; absmax canary 0.0078125).
// ---------------------------------------------------------------------------
__global__ __launch_bounds__(256) void build_kernel(
    const float* __restrict__ weight,
    const float* __restrict__ sign,
    const float* __restrict__ P,
    const float* __restrict__ SIG,
    unsigned short* __restrict__ Kh,
    unsigned short* __restrict__ Kl)
{
    __shared__ float Ws[256 * CCHUNK];   // w*sign
    __shared__ float Ps[256 * CCHUNK];   // P + 12
    __shared__ float Ss[256 * CCHUNK];   // |SIG| + 0.27

    const int tid = threadIdx.x;         // i
    const int o   = blockIdx.x;
    const int gbase = o * IN_C * KC;     // block's contiguous span (floats)

    float K[KD];
#pragma unroll
    for (int d = 0; d < KD; ++d) K[d] = 0.f;

#pragma unroll 1
    for (int cc = 0; cc < KC; cc += CCHUNK) {
        __syncthreads();   // previous chunk's LDS reads done
        for (int q = tid; q < 256 * CCHUNK; q += 256) {
            const int p = q / CCHUNK;
            const int c = q - p * CCHUNK;
            const int gidx = gbase + p * KC + cc + c;
            Ws[q] = weight[gidx] * sign[gidx];
            Ps[q] = P[gidx] + (float)(KD / 2);
            Ss[q] = fabsf(SIG[gidx]) + 0.27f;
        }
        __syncthreads();

#pragma unroll 1
        for (int c = 0; c < CCHUNK; ++c) {
            const float w   = Ws[tid * CCHUNK + c];
            const float pc  = Ps[tid * CCHUNK + c];
            const float s   = Ss[tid * CCHUNK + c];
            const float inv = 1.f / s;
            float e[KD];
            float sum = 0.f;
#pragma unroll
            for (int d = 0; d < KD; ++d) {
                const float t = ((float)d - pc) * inv;
                e[d] = __expf(-0.5f * t * t);
                sum += e[d];
            }
            const float wn = w / (sum + 1e-7f);
#pragma unroll
            for (int d = 0; d < KD; ++d) K[d] += wn * e[d];
        }
    }

    const int ic = tid >> 6;       // 64-i chunk
    const int il = tid & 63;       // i within chunk
#pragma unroll
    for (int d = 0; d < KD; ++d) {
        const int off = (d * NIC + ic) * SLABSZ + o * ICH + il;
        const float v = K[d];
        const unsigned short h = f2bf(v);
        const unsigned short l = f2bf(v - bf2f(h));
        Kh[off] = h;
        Kl[off] = l;
    }
}

// ---------------------------------------------------------------------------
// Kernel 2: conv1d as implicit GEMM on mfma_f32_16x16x32_bf16, 3-product
// hi/lo split. A = K streamed global->VGPR, B = x via LDS.
// v3 occupancy fix: 512 threads = 8 waves/block (was 4), wave tile
// 32o x 64l (acc[2][4]); same 512-block grid -> 16 waves/CU = 4 waves/SIMD
// (was 2). Rounds 6+7 showed MfmaUtil pinned at 33% under two different
// prefetch schedules -> latency gaps need more resident waves, not better
// placement. Live regs ~106 <= 128 so __launch_bounds__(512,4) holds.
// ---------------------------------------------------------------------------
__global__ __launch_bounds__(512, 4) void conv_kernel(
    const float* __restrict__ x,
    const unsigned short* __restrict__ Kh,
    const unsigned short* __restrict__ Kl,
    float* __restrict__ out)
{
    __shared__ __align__(16) unsigned short xs_h[XROWS * ICH];  // 19456 B
    __shared__ __align__(16) unsigned short xs_l[XROWS * ICH];

    const int tid = threadIdx.x;
    const unsigned int Bid = blockIdx.x;
    const int ot = Bid & 1;                 // o-half: fixed per XCD parity
    const int lt = (Bid >> 1) & 7;          // l tile
    const int b  = Bid >> 4;                // batch
    const int o0 = ot * BM;
    const int l0 = lt * BL;

    const int lane = tid & 63;
    const int wid  = tid >> 6;              // 0..7
    const int wm   = wid >> 1;              // o-quarter (32 o each), 0..3
    const int wn   = wid & 1;               // l-half (64 l each), 0..1
    const int n16  = lane & 15;
    const int g    = lane >> 4;             // 0..3 (k-group)

    // lane-fixed element offset of this lane's A-fragment within a K slab
    const int kbase = (o0 + wm * 32 + n16) * ICH + g * 8;

    f32x4 acc[2][4] = {};
    bf16x8 A0h[2], A0l[2], A1h[2], A1l[2];  // kt-phase double buffer

#define LOAD_MT(BH, BL_, SLAB, KT, MT)                                    \
    {                                                                     \
        const int _e = (SLAB) * SLABSZ + kbase + (KT) * 32 + (MT) * (16 * ICH); \
        BH[MT]  = *(const bf16x8*)&Kh[_e];                                \
        BL_[MT] = *(const bf16x8*)&Kl[_e];                                \
    }

// one kt-phase: read B frags, then 2 mt-sections of
// [issue next-phase A-load for mt; 12 MFMAs on current A[mt]]
#define PHASE(CH, CL, NH, NL, KT, NSLAB, NKT, D)                          \
    {                                                                     \
        bf16x8 bh[4], bl[4];                                              \
        _Pragma("unroll")                                                 \
        for (int nt = 0; nt < 4; ++nt) {                                  \
            const int row  = wn * 64 + nt * 16 + n16 + (D);               \
            const int slot = ((KT) * 4 + g) ^ (row & 7);                  \
            const int pos  = row * ICH + slot * 8;                        \
            bh[nt] = *(const bf16x8*)&xs_h[pos];                          \
            bl[nt] = *(const bf16x8*)&xs_l[pos];                          \
        }                                                                 \
        _Pragma("unroll")                                                 \
        for (int mt = 0; mt < 2; ++mt) {                                  \
            LOAD_MT(NH, NL, NSLAB, NKT, mt);                              \
            _Pragma("unroll")                                             \
            for (int nt = 0; nt < 4; ++nt) {                              \
                acc[mt][nt] = __builtin_amdgcn_mfma_f32_16x16x32_bf16(    \
                    CL[mt], bh[nt], acc[mt][nt], 0, 0, 0);                \
                acc[mt][nt] = __builtin_amdgcn_mfma_f32_16x16x32_bf16(    \
                    CH[mt], bl[nt], acc[mt][nt], 0, 0, 0);                \
                acc[mt][nt] = __builtin_amdgcn_mfma_f32_16x16x32_bf16(    \
                    CH[mt], bh[nt], acc[mt][nt], 0, 0, 0);                \
            }                                                             \
        }                                                                 \
    }

    // prologue: load phase-0 (ic=0, d=0, kt=0) A-fragments
    int slab = 0;                            // slab index = d*NIC + ic
#pragma unroll
    for (int mt = 0; mt < 2; ++mt) LOAD_MT(A0h, A0l, 0, 0, mt);

#pragma unroll 1
    for (int ic = 0; ic < NIC; ++ic) {
        // ---- stage x chunk: transpose + hi/lo split + XOR swizzle
        const int xbase = (b * IN_C + ic * ICH) * LEN;
        for (int idx = tid; idx < (ICH / 8) * XROWS; idx += 512) {   // 1216
            const int c8 = idx / XROWS;          // i octave 0..7
            const int r  = idx - c8 * XROWS;     // l row 0..151
            const int gl = l0 + r;
            const int ci = c8 * 8;
            float v[8];
#pragma unroll
            for (int j = 0; j < 8; ++j)
                v[j] = (gl < LEN) ? x[xbase + (ci + j) * LEN + gl] : 0.f;
            unsigned int ph[4], pl[4];
#pragma unroll
            for (int j = 0; j < 4; ++j) {
                const unsigned short h0  = f2bf(v[2 * j]);
                const unsigned short h1  = f2bf(v[2 * j + 1]);
                const unsigned short l0s = f2bf(v[2 * j] - bf2f(h0));
                const unsigned short l1s = f2bf(v[2 * j + 1] - bf2f(h1));
                ph[j] = (unsigned int)h0 | ((unsigned int)h1 << 16);
                pl[j] = (unsigned int)l0s | ((unsigned int)l1s << 16);
            }
            const int slot = r * 8 + (c8 ^ (r & 7));    // uint4 index
            ((uint4*)xs_h)[slot] = make_uint4(ph[0], ph[1], ph[2], ph[3]);
            ((uint4*)xs_l)[slot] = make_uint4(pl[0], pl[1], pl[2], pl[3]);
        }
        __syncthreads();   // xs visible; no LDS writes until after d-loop

#pragma unroll 1
        for (int d = 0; d < KD; ++d) {
            const int slabNext = (d < KD - 1) ? slab + NIC
                               : (ic < NIC - 1 ? ic + 1 : slab);
            // compute kt=0 from A0 (loaded during previous phase),
            // issue kt=1 loads of this slab into A1 (interleaved per-mt)
            PHASE(A0h, A0l, A1h, A1l, 0, slab, 1, d);
            // compute kt=1 from A1, issue next slab's kt=0 into A0
            PHASE(A1h, A1l, A0h, A0l, 1, slabNext, 0, d);
            slab = slabNext;
        }
        __syncthreads();   // all xs reads done before next chunk overwrites
    }

#undef LOAD_MT
#undef PHASE

    // ---- epilogue: C/D layout col=lane&15 (=l), row=(lane>>4)*4+reg (=o)
#pragma unroll
    for (int mt = 0; mt < 2; ++mt)
#pragma unroll
        for (int nt = 0; nt < 4; ++nt) {
            const int l = l0 + wn * 64 + nt * 16 + n16;
            if (l < LOUT) {
#pragma unroll
                for (int r = 0; r < 4; ++r) {
                    const int o = o0 + wm * 32 + mt * 16 + g * 4 + r;
                    out[(b * OUT_C + o) * LOUT + l] = acc[mt][nt][r];
                }
            }
        }
}

// ---------------------------------------------------------------------------
extern "C" void kernel_launch(void* const* d_in, const int* in_sizes, int n_in,
                              void* d_out, int out_size, void* d_ws, size_t ws_size,
                              hipStream_t stream)
{
    (void)in_sizes; (void)n_in; (void)out_size; (void)ws_size;

    const float* x      = (const float*)d_in[0];
    const float* weight = (const float*)d_in[1];
    const float* sign   = (const float*)d_in[2];
    const float* P      = (const float*)d_in[3];
    const float* SIG    = (const float*)d_in[4];
    float*       out    = (float*)d_out;

    // workspace: Kh then Kl, each 25*4*256*64 = 1,638,400 bf16 (3.28 MB)
    unsigned short* Kh = (unsigned short*)d_ws;
    unsigned short* Kl = Kh + (size_t)KD * NIC * SLABSZ;

    // one block per o; inputs LDS-staged coalesced
    build_kernel<<<dim3(OUT_C), dim3(256), 0, stream>>>(
        weight, sign, P, SIG, Kh, Kl);

    // 512 blocks x 512 threads: Bid&1 = o-half (constant per XCD under %8
    // round-robin), bits1-3 = l tile, bits4+ = batch
    conv_kernel<<<dim3(512), dim3(512), 0, stream>>>(x, Kh, Kl, out);
}